// Round 5
// baseline (62.326 us; speedup 1.0000x reference)
//
#include <hip/hip_runtime.h>

// 21-qubit HEA, fp32, all-real. ONE kernel, 1024 blocks x 256 threads.
// R13: ZERO-BARRIER wave-autonomous rewrite. R1/R3/R4 post-mortems show
// the kernel stuck ~4x above its throughput floor; the remaining cost is
// the 5-barrier lockstep (every LDS exchange = CU-wide drain bubble).
// Move the U1/U2 boundary to bit 8 so ONE WAVE owns a full 512-state slab
// (regs x8..x6, lanes x5..x0): reg-bit gates via ry_bf/cnot_rr, lane-bit
// gates via ry_shfl/cnot_shfl (helpers verified in the R0 kernel), and
// the reg<->lane CNOT C14 is 4 bare shfl_xor(.,32). No LDS exchanges, no
// barriers after csn staging.
// Factorization: U_total = U2*U1*|init>,
//   U1 = {RY2 q0..q12, C0..C11, RY3 q0..q11}  acts on bits 20..8,
//   U2 = {RY2 q13..q20, C12..C19, RY3 q12..q20} acts on bits 8..0.
// Commutation (disjoint bits): RY2 q13..20 (bits 7..0) move right past
// C0..C11 (bits 20..8) and RY3 q0..q11 (bits 20..9); RY3 q0..q11 moves
// left past C12..C19 (bits 8..0).  [C11=(9,8), C12=(8,7).]
// U1 -> a(x8,c) via 13-site 4-state transfer matrix (wave-uniform, ~220
// FMA, zero cross-lane): slab = x20..x9 (12 bits) = (blockIdx<<2)|wave;
// b*_q = slab_{11-q} (q=0..11); boundary site 12: RY1 p12, RY2 p33;
// W[x8][x7] = a(x8,0)*sel(p13,x7) + a(x8,1)*sel(p13,~x7).
// init (layer1+chain1 Gray links below the boundary):
//   v[r] = W[x8][x7] * sel(p14, x6^x7) * sel(p15, x5^x6)
//          * prod_{b=0..4} sel(p_{20-b}, lane-gray_b),  t=(r<<6)|lane.
// U2 gate ledger (order = RY2 all, C12..C19 in chain order, RY3 all):
//   RY2 p34 b7=r1, p35 b6=r0, p36..p41 lane bits 5..0 (shfl 32..1);
//   C12 (8,7) rr<2,1>; C13 (7,6) rr<1,0>; C14 (6,5) odd-reg shfl_xor 32;
//   C15..C19 lane-lane cnot_shfl <32,16><16,8><8,4><4,2><2,1>;
//   RY3 p54 b8=r2, p55 b7=r1, p56 b6=r0, p57..p62 lane bits 5..0.
// Param audit: RY1 p0..p12 TM, p13 W, p14 per-r, p15 lane/r, p16..p20
// lane-gray (21); RY2 p21..p33 TM, p34..41 gates (21); RY3 p42..p53 TM,
// p54..62 gates (21); CNOT C0..C11 TM prefix-xor, C12..C19 gates (20).
// qubit q <-> bit 20-q; params RY1 q->p[q], RY2 q->p[21+q], RY3 q->p[42+q].
// Norm == 1 by unitarity.

#define NQ 21
#define NSTATE (1 << NQ)

typedef float f32x2 __attribute__((ext_vector_type(2)));

template <int BIT, int N>
__device__ __forceinline__ void ry_bf(float (&v)[N], float c, float s) {
#pragma unroll
  for (int m = 0; m < N; ++m)
    if ((m & (1 << BIT)) == 0) {
      float a = v[m], b = v[m | (1 << BIT)];
      v[m] = c * a - s * b;
      v[m | (1 << BIT)] = s * a + c * b;
    }
}

template <int CBIT, int TBIT, int N>
__device__ __forceinline__ void cnot_rr(float (&v)[N]) {
#pragma unroll
  for (int m = 0; m < N; ++m)
    if ((m & (1 << CBIT)) && !(m & (1 << TBIT))) {
      float t = v[m];
      v[m] = v[m | (1 << TBIT)];
      v[m | (1 << TBIT)] = t;
    }
}

// RY on a bit living in the LANE index (shfl butterfly). Verified in R0.
template <int MASK, int N>
__device__ __forceinline__ void ry_shfl(float (&u)[N], float c, float s,
                                        int lane) {
  const float ss = (lane & MASK) ? s : -s;
#pragma unroll
  for (int e = 0; e < N; ++e) {
    float w = __shfl_xor(u[e], MASK);
    u[e] = c * u[e] + ss * w;
  }
}

// CNOT: ctrl lane-bit mask CMASK, tgt lane-bit mask TMASK. Verified in R0.
template <int CMASK, int TMASK, int N>
__device__ __forceinline__ void cnot_shfl(float (&u)[N], int lane) {
  const bool ctrl = (lane & CMASK) != 0;
#pragma unroll
  for (int e = 0; e < N; ++e) {
    float w = __shfl_xor(u[e], TMASK);
    u[e] = ctrl ? w : u[e];
  }
}

__global__ __launch_bounds__(256, 4) void fused(const float* __restrict__ p,
                                                float* __restrict__ out,
                                                int outmode) {
  __shared__ float2 csn[63];    // (cos, sin) pairs -> b64 broadcast reads
  const int tid = threadIdx.x;  // 8 bits; waves independent after B0
  if (tid < 63) {
    float h = 0.5f * p[tid];
    csn[tid] = float2{cosf(h), sinf(h)};
  }
  __syncthreads();  // B0 -- the ONLY barrier

  const int lane = tid & 63;                         // x5..x0
  const int slab = (blockIdx.x << 2) | (tid >> 6);   // 12 bits: x20..x9

  // ===== Phase 1: 13-site transfer-matrix contraction for a(x8,c) =====
  float W[2][2];
  {
    const int b0 = (slab >> 11) & 1;
    const float2 g30 = csn[42], g20 = csn[21], g10 = csn[0];
    const float r00 = b0 ? g30.y : g30.x;
    const float r01 = b0 ? g30.x : -g30.y;
    float w00 = r00 * g20.x * g10.x;
    float w01 = r00 * (-g20.y) * g10.y;
    float w10 = r01 * g20.y * g10.x;
    float w11 = r01 * g20.x * g10.y;
#pragma unroll
    for (int q = 1; q <= 11; ++q) {
      const int bq = (slab >> (11 - q)) & 1;
      const float2 g1 = csn[q], g2 = csn[21 + q], g3 = csn[42 + q];
      const float c1 = g1.x, s1 = g1.y;
      const float c2 = g2.x, s2 = g2.y;
      const float c3 = g3.x, s3 = g3.y;
      const float h00 = c1 * w00 + s1 * w01;
      const float h01 = c1 * w10 + s1 * w11;
      const float h10 = s1 * w00 + c1 * w01;
      const float h11 = s1 * w10 + c1 * w11;
      const float m00 = c2 * h00 + s2 * h01;
      const float m01 = s2 * h00 + c2 * h01;
      const float m10 = -s2 * h10 + c2 * h11;
      const float m11 = c2 * h10 - s2 * h11;
      const float r0 = bq ? s3 : c3;
      const float r1 = bq ? c3 : -s3;
      w00 = r0 * m00;
      w01 = r0 * m10;
      w10 = r1 * m01;
      w11 = r1 * m11;
    }
    // boundary site 12: RY1 p12, RY2 q12 = p33; then W-link RY1 p13
    const float2 g1b = csn[12], g2b = csn[33], gW = csn[13];
    const float hh00 = g1b.x * w00 + g1b.y * w01;
    const float hh01 = g1b.x * w10 + g1b.y * w11;
    const float hh10 = g1b.y * w00 + g1b.x * w01;
    const float hh11 = g1b.y * w10 + g1b.x * w11;
    const float a00 = g2b.x * hh00 + g2b.y * hh01;
    const float a10 = g2b.y * hh00 + g2b.x * hh01;
    const float a01 = -g2b.y * hh10 + g2b.x * hh11;
    const float a11 = g2b.x * hh10 - g2b.y * hh11;
    W[0][0] = a00 * gW.x + a01 * gW.y;
    W[0][1] = a00 * gW.y + a01 * gW.x;
    W[1][0] = a10 * gW.x + a11 * gW.y;
    W[1][1] = a10 * gW.y + a11 * gW.x;
  }

  // ===== Phase 2 init: regs r2r1r0 = x8x7x6, lanes = x5..x0 =====
  float v[8];
  {
    const int gl = lane ^ (lane >> 1);  // bits b=0..4: x_b ^ x_{b+1}
    float tlane = 1.0f;
#pragma unroll
    for (int b = 0; b < 5; ++b) {
      const float2 gb = csn[20 - b];
      tlane *= ((gl >> b) & 1) ? gb.y : gb.x;
    }
    const int x5 = (lane >> 5) & 1;
    const float2 g15 = csn[15], g14 = csn[14];
    const float s15_0 = x5 ? g15.y : g15.x;  // link x5^x6, r0=0
    const float s15_1 = x5 ? g15.x : g15.y;  // link x5^x6, r0=1
#pragma unroll
    for (int r = 0; r < 8; ++r) {
      float prod = tlane * W[(r >> 2) & 1][(r >> 1) & 1];
      prod *= (r & 1) ? s15_1 : s15_0;                  // p15: x5^x6
      prod *= ((r ^ (r >> 1)) & 1) ? g14.y : g14.x;     // p14: x6^x7
      v[r] = prod;
    }
  }

  // ===== U2 gates (wave-local, zero barriers) =====
  // RY2 q13..q20
  ry_bf<1>(v, csn[34].x, csn[34].y);          // b7
  ry_bf<0>(v, csn[35].x, csn[35].y);          // b6
  ry_shfl<32>(v, csn[36].x, csn[36].y, lane); // b5
  ry_shfl<16>(v, csn[37].x, csn[37].y, lane); // b4
  ry_shfl<8>(v, csn[38].x, csn[38].y, lane);  // b3
  ry_shfl<4>(v, csn[39].x, csn[39].y, lane);  // b2
  ry_shfl<2>(v, csn[40].x, csn[40].y, lane);  // b1
  ry_shfl<1>(v, csn[41].x, csn[41].y, lane);  // b0
  // CNOT chain C12..C19 (in order)
  cnot_rr<2, 1>(v);  // C12 (8,7)
  cnot_rr<1, 0>(v);  // C13 (7,6)
  // C14 (6,5): ctrl r0, tgt lane bit5 -> odd regs swap across lane^32
  v[1] = __shfl_xor(v[1], 32);
  v[3] = __shfl_xor(v[3], 32);
  v[5] = __shfl_xor(v[5], 32);
  v[7] = __shfl_xor(v[7], 32);
  cnot_shfl<32, 16>(v, lane);  // C15 (5,4)
  cnot_shfl<16, 8>(v, lane);   // C16 (4,3)
  cnot_shfl<8, 4>(v, lane);    // C17 (3,2)
  cnot_shfl<4, 2>(v, lane);    // C18 (2,1)
  cnot_shfl<2, 1>(v, lane);    // C19 (1,0)
  // RY3 q12..q20
  ry_bf<2>(v, csn[54].x, csn[54].y);          // b8
  ry_bf<1>(v, csn[55].x, csn[55].y);          // b7
  ry_bf<0>(v, csn[56].x, csn[56].y);          // b6
  ry_shfl<32>(v, csn[57].x, csn[57].y, lane); // b5
  ry_shfl<16>(v, csn[58].x, csn[58].y, lane); // b4
  ry_shfl<8>(v, csn[59].x, csn[59].y, lane);  // b3
  ry_shfl<4>(v, csn[60].x, csn[60].y, lane);  // b2
  ry_shfl<2>(v, csn[61].x, csn[61].y, lane);  // b1
  ry_shfl<1>(v, csn[62].x, csn[62].y, lane);  // b0

  // Output: state index t = (slab<<9)|(r<<6)|lane; per-r stores are
  // 64-lane contiguous (256B/512B per instruction), nontemporal.
  const int base = (slab << 9) | lane;
  if (outmode == 2) {
    f32x2* o2 = (f32x2*)out;  // interleaved complex (re, 0)
#pragma unroll
    for (int r = 0; r < 8; ++r) {
      f32x2 w = {v[r], 0.0f};
      __builtin_nontemporal_store(w, &o2[base + (r << 6)]);
    }
  } else {
#pragma unroll
    for (int r = 0; r < 8; ++r)
      __builtin_nontemporal_store(v[r], &out[base + (r << 6)]);
  }
}

extern "C" void kernel_launch(void* const* d_in, const int* in_sizes, int n_in,
                              void* d_out, int out_size, void* d_ws,
                              size_t ws_size, hipStream_t stream) {
  const float* p = (const float*)d_in[0];  // 63 fp32 params
  float* out = (float*)d_out;
  const int outmode = (out_size == 2 * NSTATE) ? 2 : 1;
  fused<<<1024, 256, 0, stream>>>(p, out, outmode);
}

// Round 6
// 58.966 us; speedup vs baseline: 1.0570x; 1.0570x over previous
//
#include <hip/hip_runtime.h>

// 21-qubit HEA, fp32, all-real. ONE kernel, 1024 blocks x 256 threads.
// R14: wave-autonomous (ONE barrier, for csn staging) with TWO intra-wave
// LDS transposes instead of R5's 140 shuffles or R4's 4 block-wide
// exchanges+5 barriers. Evidence: R5 (+140 shfl, 0 barriers) = +2.4us vs
// R4 (64 exch LDS + 5 barriers); R3/R1 nulls. Minimize total
// {shfl + LDS + barrier} events: R6 = 32 LDS + 16 shfl + 1 barrier.
// Factorization (verified in R5, reused verbatim):
//   U1 = {RY2 q0..q12, C0..C11, RY3 q0..q11}   acts on bits 20..8,
//   U2 = {RY2 q13..q20, C12..C19, RY3 q12..q20} acts on bits 8..0.
// U1 -> a(x8,c) via 13-site transfer matrix (wave-uniform); W[x8][x7].
// Wave owns 512 states s8..s0; slab = x20..x9 = (blockIdx<<2)|(tid>>6).
// Three register windows, transposes in a private 2KB LDS region per wave
// (same-wave DS ops are in-order; explicit lgkmcnt fences guard compiler):
//   L1: regs=s8s7s6, lane=s5..s0 : init; RY2 p34(b7),p35(b6); C12(8,7),
//       C13(7,6); RY3 p54(b8),p55(b7)
//   T1 (XOR swizzle, banks: write 2-way free, read 2-way free)
//   L2: regs=s5s4s3, lane=(s8s7s6,s2s1s0) : RY2 p36(b5),p37(b4),p38(b3);
//       C14(6,5)=cswap ctrl lane-bit3; C15(5,4),C16(4,3); RY3 p56(b6)=
//       ry_shfl<8>, p57(b5), p58(b4)
//   T2 (SW swizzle, banks: write 4-way, read free)
//   L3: regs=s2s1s0, lane=s8..s3 : RY2 p39(b2),p40(b1),p41(b0);
//       C17(3,2)=cswap ctrl lane-bit0; C18(2,1),C19(1,0); RY3 p59(b3)=
//       ry_shfl<1>, p60(b2),p61(b1),p62(b0)
// Ledger audit (63 params): RY1 p0..p12 TM, p13 W, p14,p15 init-links,
// p16..p20 lane-gray (21); RY2 p21..p33 TM, p34..41 gates (21); RY3
// p42..p53 TM, p54..62 gates (21). CNOTs: C0..C11 TM prefix-xor,
// C12..C19 gates in chain order. Every RY2 precedes the first CNOT on its
// bit (p36..38 before C14..C16; p39..41 before C17..C19 -- moves commute,
// disjoint bits); every RY3 follows the last CNOT on its bit.
// L3 leaves each thread owning 8 CONSECUTIVE states -> 4x b128 stores.
// qubit q <-> bit 20-q; params RY1 q->p[q], RY2 q->p[21+q], RY3 q->p[42+q].
// Norm == 1 by unitarity.

#define NQ 21
#define NSTATE (1 << NQ)
#define SW(t) ((t) + ((t) >> 5))  // +1 word / 32 words

typedef float f32x4 __attribute__((ext_vector_type(4)));

template <int BIT, int N>
__device__ __forceinline__ void ry_bf(float (&v)[N], float c, float s) {
#pragma unroll
  for (int m = 0; m < N; ++m)
    if ((m & (1 << BIT)) == 0) {
      float a = v[m], b = v[m | (1 << BIT)];
      v[m] = c * a - s * b;
      v[m | (1 << BIT)] = s * a + c * b;
    }
}

template <int CBIT, int TBIT, int N>
__device__ __forceinline__ void cnot_rr(float (&v)[N]) {
#pragma unroll
  for (int m = 0; m < N; ++m)
    if ((m & (1 << CBIT)) && !(m & (1 << TBIT))) {
      float t = v[m];
      v[m] = v[m | (1 << TBIT)];
      v[m | (1 << TBIT)] = t;
    }
}

// CNOT with control outside the register index (cond), target reg bit.
// Verified in R0.
template <int TBIT, int N>
__device__ __forceinline__ void cswap_bf(float (&v)[N], bool cond) {
#pragma unroll
  for (int m = 0; m < N; ++m)
    if ((m & (1 << TBIT)) == 0) {
      float a = v[m], b = v[m | (1 << TBIT)];
      v[m] = cond ? b : a;
      v[m | (1 << TBIT)] = cond ? a : b;
    }
}

// RY on a bit living in the LANE index (shfl butterfly). Verified in R0.
template <int MASK, int N>
__device__ __forceinline__ void ry_shfl(float (&u)[N], float c, float s,
                                        int lane) {
  const float ss = (lane & MASK) ? s : -s;
#pragma unroll
  for (int e = 0; e < N; ++e) {
    float w = __shfl_xor(u[e], MASK);
    u[e] = c * u[e] + ss * w;
  }
}

__global__ __launch_bounds__(256, 4) void fused(const float* __restrict__ p,
                                                float* __restrict__ out,
                                                int outmode) {
  __shared__ float2 csn[63];   // (cos, sin) pairs -> b64 broadcast reads
  __shared__ float ex[4][528]; // per-wave private 512 words + SW pad
  const int tid = threadIdx.x; // 8 bits
  if (tid < 63) {
    float h = 0.5f * p[tid];
    csn[tid] = float2{cosf(h), sinf(h)};
  }
  __syncthreads();  // B0 -- the ONLY barrier

  const int lane = tid & 63;
  const int slab = (blockIdx.x << 2) | (tid >> 6);  // 12 bits: x20..x9
  float* const exw = &ex[tid >> 6][0];

  // ===== Phase 1: 13-site transfer-matrix contraction for a(x8,c) =====
  float W[2][2];
  {
    const int b0 = (slab >> 11) & 1;
    const float2 g30 = csn[42], g20 = csn[21], g10 = csn[0];
    const float r00 = b0 ? g30.y : g30.x;
    const float r01 = b0 ? g30.x : -g30.y;
    float w00 = r00 * g20.x * g10.x;
    float w01 = r00 * (-g20.y) * g10.y;
    float w10 = r01 * g20.y * g10.x;
    float w11 = r01 * g20.x * g10.y;
#pragma unroll
    for (int q = 1; q <= 11; ++q) {
      const int bq = (slab >> (11 - q)) & 1;
      const float2 g1 = csn[q], g2 = csn[21 + q], g3 = csn[42 + q];
      const float c1 = g1.x, s1 = g1.y;
      const float c2 = g2.x, s2 = g2.y;
      const float c3 = g3.x, s3 = g3.y;
      const float h00 = c1 * w00 + s1 * w01;
      const float h01 = c1 * w10 + s1 * w11;
      const float h10 = s1 * w00 + c1 * w01;
      const float h11 = s1 * w10 + c1 * w11;
      const float m00 = c2 * h00 + s2 * h01;
      const float m01 = s2 * h00 + c2 * h01;
      const float m10 = -s2 * h10 + c2 * h11;
      const float m11 = c2 * h10 - s2 * h11;
      const float r0 = bq ? s3 : c3;
      const float r1 = bq ? c3 : -s3;
      w00 = r0 * m00;
      w01 = r0 * m10;
      w10 = r1 * m01;
      w11 = r1 * m11;
    }
    // boundary site 12: RY1 p12, RY2 q12 = p33; then W-link RY1 p13
    const float2 g1b = csn[12], g2b = csn[33], gW = csn[13];
    const float hh00 = g1b.x * w00 + g1b.y * w01;
    const float hh01 = g1b.x * w10 + g1b.y * w11;
    const float hh10 = g1b.y * w00 + g1b.x * w01;
    const float hh11 = g1b.y * w10 + g1b.x * w11;
    const float a00 = g2b.x * hh00 + g2b.y * hh01;
    const float a10 = g2b.y * hh00 + g2b.x * hh01;
    const float a01 = -g2b.y * hh10 + g2b.x * hh11;
    const float a11 = g2b.x * hh10 - g2b.y * hh11;
    W[0][0] = a00 * gW.x + a01 * gW.y;
    W[0][1] = a00 * gW.y + a01 * gW.x;
    W[1][0] = a10 * gW.x + a11 * gW.y;
    W[1][1] = a10 * gW.y + a11 * gW.x;
  }

  // ===== L1 init: regs r2r1r0 = s8s7s6, lanes = s5..s0 (verbatim R5) ====
  float v[8];
  {
    const int gl = lane ^ (lane >> 1);  // bits b=0..4: s_b ^ s_{b+1}
    float tlane = 1.0f;
#pragma unroll
    for (int b = 0; b < 5; ++b) {
      const float2 gb = csn[20 - b];
      tlane *= ((gl >> b) & 1) ? gb.y : gb.x;
    }
    const int x5 = (lane >> 5) & 1;
    const float2 g15 = csn[15], g14 = csn[14];
    const float s15_0 = x5 ? g15.y : g15.x;  // link s5^s6, r0=0
    const float s15_1 = x5 ? g15.x : g15.y;  // link s5^s6, r0=1
#pragma unroll
    for (int r = 0; r < 8; ++r) {
      float prod = tlane * W[(r >> 2) & 1][(r >> 1) & 1];
      prod *= (r & 1) ? s15_1 : s15_0;               // p15: s5^s6
      prod *= ((r ^ (r >> 1)) & 1) ? g14.y : g14.x;  // p14: s6^s7
      v[r] = prod;
    }
  }

  // ===== L1 gates =====
  ry_bf<1>(v, csn[34].x, csn[34].y);  // RY2 p34 (b7)
  ry_bf<0>(v, csn[35].x, csn[35].y);  // RY2 p35 (b6)
  cnot_rr<2, 1>(v);                   // C12 (8,7)
  cnot_rr<1, 0>(v);                   // C13 (7,6)
  ry_bf<2>(v, csn[54].x, csn[54].y);  // RY3 p54 (b8)
  ry_bf<1>(v, csn[55].x, csn[55].y);  // RY3 p55 (b7)

  // ===== T1: L1 -> L2 (XOR swizzle; write free, read 2-way free) =====
#pragma unroll
  for (int r = 0; r < 8; ++r)
    exw[(r << 6) | (lane ^ (r << 3))] = v[r];
  asm volatile("s_waitcnt lgkmcnt(0)" ::: "memory");
  {
    const int h = lane >> 3, w = lane & 7;
#pragma unroll
    for (int r = 0; r < 8; ++r)
      v[r] = exw[(h << 6) | ((r ^ h) << 3) | w];
  }

  // ===== L2 gates: regs = s5s4s3, lane = (s8s7s6, s2s1s0) =====
  ry_bf<2>(v, csn[36].x, csn[36].y);         // RY2 p36 (b5)
  ry_bf<1>(v, csn[37].x, csn[37].y);         // RY2 p37 (b4)
  ry_bf<0>(v, csn[38].x, csn[38].y);         // RY2 p38 (b3)
  cswap_bf<2>(v, (lane & 8) != 0);           // C14 (6,5): ctrl s6=lane b3
  cnot_rr<2, 1>(v);                          // C15 (5,4)
  cnot_rr<1, 0>(v);                          // C16 (4,3)
  ry_shfl<8>(v, csn[56].x, csn[56].y, lane); // RY3 p56 (b6 = lane b3)
  ry_bf<2>(v, csn[57].x, csn[57].y);         // RY3 p57 (b5)
  ry_bf<1>(v, csn[58].x, csn[58].y);         // RY3 p58 (b4)

  // ===== T2: L2 -> L3 (SW swizzle; write 4-way, read free) =====
  asm volatile("s_waitcnt lgkmcnt(0)" ::: "memory");  // T1 reads retired
  {
    const int h = lane >> 3, w = lane & 7;
#pragma unroll
    for (int r = 0; r < 8; ++r) {
      const int t = (h << 6) | (r << 3) | w;
      exw[SW(t)] = v[r];
    }
  }
  asm volatile("s_waitcnt lgkmcnt(0)" ::: "memory");
#pragma unroll
  for (int r = 0; r < 8; ++r) {
    const int t = (lane << 3) | r;
    v[r] = exw[SW(t)];
  }

  // ===== L3 gates: regs = s2s1s0, lane = s8..s3 =====
  ry_bf<2>(v, csn[39].x, csn[39].y);         // RY2 p39 (b2)
  ry_bf<1>(v, csn[40].x, csn[40].y);         // RY2 p40 (b1)
  ry_bf<0>(v, csn[41].x, csn[41].y);         // RY2 p41 (b0)
  cswap_bf<2>(v, (lane & 1) != 0);           // C17 (3,2): ctrl s3=lane b0
  cnot_rr<2, 1>(v);                          // C18 (2,1)
  cnot_rr<1, 0>(v);                          // C19 (1,0)
  ry_shfl<1>(v, csn[59].x, csn[59].y, lane); // RY3 p59 (b3 = lane b0)
  ry_bf<2>(v, csn[60].x, csn[60].y);         // RY3 p60 (b2)
  ry_bf<1>(v, csn[61].x, csn[61].y);         // RY3 p61 (b1)
  ry_bf<0>(v, csn[62].x, csn[62].y);         // RY3 p62 (b0)

  // Output: thread owns 8 CONSECUTIVE states -> b128 nontemporal stores.
  const int base = (slab << 9) | (lane << 3);
  if (outmode == 2) {
    f32x4* o4 = (f32x4*)out;  // interleaved complex (re, 0)
#pragma unroll
    for (int i = 0; i < 4; ++i) {
      f32x4 w = {v[2 * i], 0.0f, v[2 * i + 1], 0.0f};
      __builtin_nontemporal_store(w, &o4[(base >> 1) + i]);
    }
  } else {
    f32x4* o4 = (f32x4*)(out + base);
#pragma unroll
    for (int j = 0; j < 2; ++j) {
      f32x4 w = {v[4 * j], v[4 * j + 1], v[4 * j + 2], v[4 * j + 3]};
      __builtin_nontemporal_store(w, &o4[j]);
    }
  }
}

extern "C" void kernel_launch(void* const* d_in, const int* in_sizes, int n_in,
                              void* d_out, int out_size, void* d_ws,
                              size_t ws_size, hipStream_t stream) {
  const float* p = (const float*)d_in[0];  // 63 fp32 params
  float* out = (float*)d_out;
  const int outmode = (out_size == 2 * NSTATE) ? 2 : 1;
  fused<<<1024, 256, 0, stream>>>(p, out, outmode);
}

// Round 8
// 58.797 us; speedup vs baseline: 1.0600x; 1.0029x over previous
//
#include <hip/hip_runtime.h>

// 21-qubit HEA, fp32, all-real. ONE kernel, 1024 blocks x 256 threads.
// R15 = R14 (verified) + coefficient-fetch diet, arithmetic bit-identical:
//  (a) TM tables site-packed: tmA[q]=(c1,s1,c2,s2) b128 + tmB[q]=(c3,s3)
//      b64 -> 2 LDS reads/site instead of 3 (39 -> 26 for the TM).
//  (b) gate/init coefficient pairs read as explicit float4 (b128) where
//      even-aligned: (34,35),(54,55),(36,37),(56,57),(40,41),(60,61),
//      (14,15),(16,17),(18,19).
//  (c) WAR-only lgkmcnt fence between T1-reads and T2-writes removed
//      (per-wave DS ops are in-order; compiler can't reorder aliasing
//      stores above loads). Both RAW fences kept.
//  (Resubmitted unchanged: R7 bench was an infra failure -- container
//   acquisition died twice; no compile/correctness signal.)
// Structure (verified R14): wave-autonomous, ONE barrier (csn staging).
//   U1 = {RY2 q0..q12, C0..C11, RY3 q0..q11}   acts on bits 20..8,
//   U2 = {RY2 q13..q20, C12..C19, RY3 q12..q20} acts on bits 8..0.
// U1 -> a(x8,c) via 13-site transfer matrix (wave-uniform); W[x8][x7].
// Wave owns 512 states s8..s0; slab = x20..x9 = (blockIdx<<2)|(tid>>6).
// Windows: L1 regs=s8s7s6 -> T1 (XOR swizzle) -> L2 regs=s5s4s3 ->
// T2 (SW swizzle) -> L3 regs=s2s1s0. Gate ledger audited in R14 (63
// params: RY1 p0..p12 TM, p13 W, p14..p20 init; RY2 p21..p33 TM,
// p34..41 gates; RY3 p42..p53 TM, p54..62 gates; C0..C11 TM prefix-xor,
// C12..C19 gates in chain order).
// qubit q <-> bit 20-q; params RY1 q->p[q], RY2 q->p[21+q], RY3 q->p[42+q].
// Norm == 1 by unitarity.

#define NQ 21
#define NSTATE (1 << NQ)
#define SW(t) ((t) + ((t) >> 5))  // +1 word / 32 words

typedef float f32x4 __attribute__((ext_vector_type(4)));

template <int BIT, int N>
__device__ __forceinline__ void ry_bf(float (&v)[N], float c, float s) {
#pragma unroll
  for (int m = 0; m < N; ++m)
    if ((m & (1 << BIT)) == 0) {
      float a = v[m], b = v[m | (1 << BIT)];
      v[m] = c * a - s * b;
      v[m | (1 << BIT)] = s * a + c * b;
    }
}

template <int CBIT, int TBIT, int N>
__device__ __forceinline__ void cnot_rr(float (&v)[N]) {
#pragma unroll
  for (int m = 0; m < N; ++m)
    if ((m & (1 << CBIT)) && !(m & (1 << TBIT))) {
      float t = v[m];
      v[m] = v[m | (1 << TBIT)];
      v[m | (1 << TBIT)] = t;
    }
}

// CNOT with control outside the register index (cond), target reg bit.
template <int TBIT, int N>
__device__ __forceinline__ void cswap_bf(float (&v)[N], bool cond) {
#pragma unroll
  for (int m = 0; m < N; ++m)
    if ((m & (1 << TBIT)) == 0) {
      float a = v[m], b = v[m | (1 << TBIT)];
      v[m] = cond ? b : a;
      v[m | (1 << TBIT)] = cond ? a : b;
    }
}

// RY on a bit living in the LANE index (shfl butterfly).
template <int MASK, int N>
__device__ __forceinline__ void ry_shfl(float (&u)[N], float c, float s,
                                        int lane) {
  const float ss = (lane & MASK) ? s : -s;
#pragma unroll
  for (int e = 0; e < N; ++e) {
    float w = __shfl_xor(u[e], MASK);
    u[e] = c * u[e] + ss * w;
  }
}

__global__ __launch_bounds__(256, 4) void fused(const float* __restrict__ p,
                                                float* __restrict__ out,
                                                int outmode) {
  __shared__ __align__(16) float2 csn[64];  // (cos,sin); [63] pad
  __shared__ float4 tmA[13];  // site q: (c1_q, s1_q, c2_q, s2_q)
  __shared__ float2 tmB[13];  // site q: (c3_q, s3_q)   (q=12 unused)
  __shared__ float ex[4][528];  // per-wave private 512 words + SW pad
  const int tid = threadIdx.x;  // 8 bits
  if (tid < 63) {
    float h = 0.5f * p[tid];
    const float c = cosf(h), s = sinf(h);
    csn[tid] = float2{c, s};
    if (tid < 13) {
      tmA[tid].x = c;
      tmA[tid].y = s;
    } else if (tid >= 21 && tid < 34) {
      tmA[tid - 21].z = c;
      tmA[tid - 21].w = s;
    } else if (tid >= 42 && tid < 54) {
      tmB[tid - 42] = float2{c, s};
    }
  }
  __syncthreads();  // B0 -- the ONLY barrier

  const int lane = tid & 63;
  const int slab = (blockIdx.x << 2) | (tid >> 6);  // 12 bits: x20..x9
  float* const exw = &ex[tid >> 6][0];
  const float4* const csn4 = (const float4*)csn;

  // ===== Phase 1: 13-site transfer-matrix contraction for a(x8,c) =====
  float W[2][2];
  {
    const int b0 = (slab >> 11) & 1;
    const float4 gA0 = tmA[0];  // (c1,s1,c2,s2) site 0
    const float2 gB0 = tmB[0];  // (c3,s3) site 0
    const float r00 = b0 ? gB0.y : gB0.x;
    const float r01 = b0 ? gB0.x : -gB0.y;
    float w00 = r00 * gA0.z * gA0.x;
    float w01 = r00 * (-gA0.w) * gA0.y;
    float w10 = r01 * gA0.w * gA0.x;
    float w11 = r01 * gA0.z * gA0.y;
#pragma unroll
    for (int q = 1; q <= 11; ++q) {
      const int bq = (slab >> (11 - q)) & 1;
      const float4 gA = tmA[q];
      const float2 gB = tmB[q];
      const float c1 = gA.x, s1 = gA.y;
      const float c2 = gA.z, s2 = gA.w;
      const float c3 = gB.x, s3 = gB.y;
      const float h00 = c1 * w00 + s1 * w01;
      const float h01 = c1 * w10 + s1 * w11;
      const float h10 = s1 * w00 + c1 * w01;
      const float h11 = s1 * w10 + c1 * w11;
      const float m00 = c2 * h00 + s2 * h01;
      const float m01 = s2 * h00 + c2 * h01;
      const float m10 = -s2 * h10 + c2 * h11;
      const float m11 = c2 * h10 - s2 * h11;
      const float r0 = bq ? s3 : c3;
      const float r1 = bq ? c3 : -s3;
      w00 = r0 * m00;
      w01 = r0 * m10;
      w10 = r1 * m01;
      w11 = r1 * m11;
    }
    // boundary site 12: RY1 p12 + RY2 p33 = tmA[12]; W-link p13 = csn[13]
    const float4 gAb = tmA[12];
    const float2 gW = csn[13];
    const float hh00 = gAb.x * w00 + gAb.y * w01;
    const float hh01 = gAb.x * w10 + gAb.y * w11;
    const float hh10 = gAb.y * w00 + gAb.x * w01;
    const float hh11 = gAb.y * w10 + gAb.x * w11;
    const float a00 = gAb.z * hh00 + gAb.w * hh01;
    const float a10 = gAb.w * hh00 + gAb.z * hh01;
    const float a01 = -gAb.w * hh10 + gAb.z * hh11;
    const float a11 = gAb.z * hh10 - gAb.w * hh11;
    W[0][0] = a00 * gW.x + a01 * gW.y;
    W[0][1] = a00 * gW.y + a01 * gW.x;
    W[1][0] = a10 * gW.x + a11 * gW.y;
    W[1][1] = a10 * gW.y + a11 * gW.x;
  }

  // ===== L1 init: regs r2r1r0 = s8s7s6, lanes = s5..s0 =====
  float v[8];
  {
    const int gl = lane ^ (lane >> 1);  // bits b=0..4: s_b ^ s_{b+1}
    const float4 g1415 = csn4[7];  // (c14,s14,c15,s15)
    const float4 g1617 = csn4[8];  // (c16,s16,c17,s17)
    const float4 g1819 = csn4[9];  // (c18,s18,c19,s19)
    const float2 g20v = csn[20];
    // same multiply order as R14: csn[20],19,18,17,16
    float tlane = ((gl & 1) ? g20v.y : g20v.x);
    tlane *= ((gl >> 1) & 1) ? g1819.w : g1819.z;  // csn[19]
    tlane *= ((gl >> 2) & 1) ? g1819.y : g1819.x;  // csn[18]
    tlane *= ((gl >> 3) & 1) ? g1617.w : g1617.z;  // csn[17]
    tlane *= ((gl >> 4) & 1) ? g1617.y : g1617.x;  // csn[16]
    const int x5 = (lane >> 5) & 1;
    const float s15_0 = x5 ? g1415.w : g1415.z;  // link s5^s6, r0=0
    const float s15_1 = x5 ? g1415.z : g1415.w;  // link s5^s6, r0=1
#pragma unroll
    for (int r = 0; r < 8; ++r) {
      float prod = tlane * W[(r >> 2) & 1][(r >> 1) & 1];
      prod *= (r & 1) ? s15_1 : s15_0;                     // p15: s5^s6
      prod *= ((r ^ (r >> 1)) & 1) ? g1415.y : g1415.x;    // p14: s6^s7
      v[r] = prod;
    }
  }

  // ===== L1 gates =====
  {
    const float4 g3435 = csn4[17];  // (c34,s34,c35,s35)
    const float4 g5455 = csn4[27];  // (c54,s54,c55,s55)
    ry_bf<1>(v, g3435.x, g3435.y);  // RY2 p34 (b7)
    ry_bf<0>(v, g3435.z, g3435.w);  // RY2 p35 (b6)
    cnot_rr<2, 1>(v);               // C12 (8,7)
    cnot_rr<1, 0>(v);               // C13 (7,6)
    ry_bf<2>(v, g5455.x, g5455.y);  // RY3 p54 (b8)
    ry_bf<1>(v, g5455.z, g5455.w);  // RY3 p55 (b7)
  }

  // ===== T1: L1 -> L2 (XOR swizzle; write free, read 2-way free) =====
#pragma unroll
  for (int r = 0; r < 8; ++r)
    exw[(r << 6) | (lane ^ (r << 3))] = v[r];
  asm volatile("s_waitcnt lgkmcnt(0)" ::: "memory");  // RAW: writes->reads
  {
    const int h = lane >> 3, w = lane & 7;
#pragma unroll
    for (int r = 0; r < 8; ++r)
      v[r] = exw[(h << 6) | ((r ^ h) << 3) | w];
  }

  // ===== L2 gates: regs = s5s4s3, lane = (s8s7s6, s2s1s0) =====
  {
    const float4 g3637 = csn4[18];  // (c36,s36,c37,s37)
    const float2 g38 = csn[38];
    const float4 g5657 = csn4[28];  // (c56,s56,c57,s57)
    const float2 g58 = csn[58];
    ry_bf<2>(v, g3637.x, g3637.y);            // RY2 p36 (b5)
    ry_bf<1>(v, g3637.z, g3637.w);            // RY2 p37 (b4)
    ry_bf<0>(v, g38.x, g38.y);                // RY2 p38 (b3)
    cswap_bf<2>(v, (lane & 8) != 0);          // C14 (6,5): ctrl s6=lane b3
    cnot_rr<2, 1>(v);                         // C15 (5,4)
    cnot_rr<1, 0>(v);                         // C16 (4,3)
    ry_shfl<8>(v, g5657.x, g5657.y, lane);    // RY3 p56 (b6 = lane b3)
    ry_bf<2>(v, g5657.z, g5657.w);            // RY3 p57 (b5)
    ry_bf<1>(v, g58.x, g58.y);                // RY3 p58 (b4)
  }

  // ===== T2: L2 -> L3 (SW swizzle; write 4-way, read free) =====
  // (WAR fence removed: per-wave DS ops are in-order; compiler cannot
  //  reorder possibly-aliasing stores above the T1 loads.)
  {
    const int h = lane >> 3, w = lane & 7;
#pragma unroll
    for (int r = 0; r < 8; ++r) {
      const int t = (h << 6) | (r << 3) | w;
      exw[SW(t)] = v[r];
    }
  }
  asm volatile("s_waitcnt lgkmcnt(0)" ::: "memory");  // RAW: writes->reads
#pragma unroll
  for (int r = 0; r < 8; ++r) {
    const int t = (lane << 3) | r;
    v[r] = exw[SW(t)];
  }

  // ===== L3 gates: regs = s2s1s0, lane = s8..s3 =====
  {
    const float2 g39 = csn[39];
    const float4 g4041 = csn4[20];  // (c40,s40,c41,s41)
    const float2 g59 = csn[59];
    const float4 g6061 = csn4[30];  // (c60,s60,c61,s61)
    const float2 g62 = csn[62];
    ry_bf<2>(v, g39.x, g39.y);              // RY2 p39 (b2)
    ry_bf<1>(v, g4041.x, g4041.y);          // RY2 p40 (b1)
    ry_bf<0>(v, g4041.z, g4041.w);          // RY2 p41 (b0)
    cswap_bf<2>(v, (lane & 1) != 0);        // C17 (3,2): ctrl s3=lane b0
    cnot_rr<2, 1>(v);                       // C18 (2,1)
    cnot_rr<1, 0>(v);                       // C19 (1,0)
    ry_shfl<1>(v, g59.x, g59.y, lane);      // RY3 p59 (b3 = lane b0)
    ry_bf<2>(v, g6061.x, g6061.y);          // RY3 p60 (b2)
    ry_bf<1>(v, g6061.z, g6061.w);          // RY3 p61 (b1)
    ry_bf<0>(v, g62.x, g62.y);              // RY3 p62 (b0)
  }

  // Output: thread owns 8 CONSECUTIVE states -> b128 nontemporal stores.
  const int base = (slab << 9) | (lane << 3);
  if (outmode == 2) {
    f32x4* o4 = (f32x4*)out;  // interleaved complex (re, 0)
#pragma unroll
    for (int i = 0; i < 4; ++i) {
      f32x4 w = {v[2 * i], 0.0f, v[2 * i + 1], 0.0f};
      __builtin_nontemporal_store(w, &o4[(base >> 1) + i]);
    }
  } else {
    f32x4* o4 = (f32x4*)(out + base);
#pragma unroll
    for (int j = 0; j < 2; ++j) {
      f32x4 w = {v[4 * j], v[4 * j + 1], v[4 * j + 2], v[4 * j + 3]};
      __builtin_nontemporal_store(w, &o4[j]);
    }
  }
}

extern "C" void kernel_launch(void* const* d_in, const int* in_sizes, int n_in,
                              void* d_out, int out_size, void* d_ws,
                              size_t ws_size, hipStream_t stream) {
  const float* p = (const float*)d_in[0];  // 63 fp32 params
  float* out = (float*)d_out;
  const int outmode = (out_size == 2 * NSTATE) ? 2 : 1;
  fused<<<1024, 256, 0, stream>>>(p, out, outmode);
}